// Round 1
// 1267.203 us; speedup vs baseline: 14.1490x; 14.1490x over previous
//
#include <hip/hip_runtime.h>

// ---------------------------------------------------------------------------
// Fused window cross-attention for MI355X (gfx950).
//   ref: q = (x Wq^T + bq) * scale ; kv = mem Wkv^T + bkv ; per-head
//        softmax(q k^T + rpb_bias) v ; out = o Wp^T + bp
// Shapes: B=4096, T=2, N=49 tokens, C=192, H=6 heads, d=32.
// One block per (b,t), 512 threads (8 waves), v_mfma_f32_16x16x32_f16.
//
// R1 change: ALL register-array indices are now compile-time constants.
// Previous version indexed a[tt&3] / bb[(tt>>2)-nt0] with tt0 = wave*6
// (runtime) -> arrays demoted to scratch -> every MFMA operand went through
// private-memory round trips (explains 10x WRITE amplification, 59% VALUBusy,
// 0.4% MfmaUtil). New tiling: wave owns mt in {mt0,mt0+1}, nt in {nt0..nt0+2}
// with named fragments; acc[][] indexed only by unrolled literal loops.
// ---------------------------------------------------------------------------

typedef _Float16 half8  __attribute__((ext_vector_type(8)));  // 4 VGPRs, one MFMA A/B frag
typedef _Float16 half4_t __attribute__((ext_vector_type(4)));
typedef float    f32x4  __attribute__((ext_vector_type(4)));  // MFMA C/D frag
typedef float    f4     __attribute__((ext_vector_type(4)));

#define NTOK  49
#define CDIM  192
#define NHEAD 6
#define SCALE 0.17677669529663687f   // 1/sqrt(32)

// ws layout (bytes):
//   WQ   f16[192*192]          @ 0       (73728)   scale folded in
//   WKV  f16[384*192]          @ 73728   (147456)
//   WPJ  f16[192*192]          @ 221184  (73728)
//   BQ   f32[192]              @ 294912  (768)     scale folded in
//   BIAS f32[6][64][64]        @ 295680  (98304)   rpb gathered via REL_IDX
// total 393984 B

__global__ void pack_kernel(const float* __restrict__ wq, const float* __restrict__ bq,
                            const float* __restrict__ wkv, const float* __restrict__ wproj,
                            const float* __restrict__ rpb,
                            _Float16* __restrict__ WQ, _Float16* __restrict__ WKV,
                            _Float16* __restrict__ WPJ, float* __restrict__ BQ,
                            float* __restrict__ BIAS)
{
    int i = blockIdx.x * blockDim.x + threadIdx.x;
    if (i < 36864) {
        WQ[i] = (_Float16)(wq[i] * SCALE);
    } else if (i < 110592) {
        int j = i - 36864;  WKV[j] = (_Float16)wkv[j];
    } else if (i < 147456) {
        int j = i - 110592; WPJ[j] = (_Float16)wproj[j];
    } else if (i < 147648) {
        int j = i - 147456; BQ[j] = bq[j] * SCALE;
    } else if (i < 147648 + 24576) {
        int j = i - 147648;
        int h  = j >> 12;        // /4096
        int qt = (j >> 6) & 63;
        int kt = j & 63;
        float v = 0.f;
        if (qt < NTOK && kt < NTOK) {
            int ih = qt / 7, iw = qt % 7, jh = kt / 7, jw = kt % 7;
            int rel = (ih - jh + 6) * 13 + (iw - jw + 6);
            v = rpb[rel * NHEAD + h];
        }
        BIAS[j] = v;
    }
}

// Fragment conventions (m89/m120-verified, 16x16x32):
//   A frag: lane holds A[m = lane&15][k = (lane>>4)*8 + j], j=0..7  (contig 16B)
//   B frag: lane holds B[k = (lane>>4)*8 + j][n = lane&15]          (contig 16B in [n][k] storage)
//   D frag: lane holds D[row = (lane>>4)*4 + r][col = lane&15]

__launch_bounds__(512)
__global__ void attn_kernel(const float* __restrict__ x, const float* __restrict__ memory,
                            const float* __restrict__ bkv, const float* __restrict__ bproj,
                            const _Float16* __restrict__ WQ, const _Float16* __restrict__ WKV,
                            const _Float16* __restrict__ WPJ, const float* __restrict__ BQ,
                            const float* __restrict__ BIAS, float* __restrict__ out)
{
    // Row strides padded: 200 f16 = 400 B (16B-aligned, stride 100 dw == 4 mod 32 -> 2-way, free)
    __shared__ __align__(16) _Float16 XM[64][200];     // x -> mem -> attention output O
    __shared__ __align__(16) _Float16 Qs[64][200];     // q*scale + bq   [tok][feat]
    __shared__ __align__(16) _Float16 Ks[64][200];     // k + bkv        [tok][feat]
    __shared__ __align__(16) _Float16 Vs[192][72];     // v + bkv        [feat][tok] (transposed)
    __shared__ __align__(16) _Float16 Ps[2][64][72];   // softmax probs  [qt][kt], per concurrent head

    const int tid  = threadIdx.x;
    const int lane = tid & 63;
    const int wave = tid >> 6;          // 0..7
    const int l16  = lane & 15;
    const int lq   = lane >> 4;         // quad 0..3
    const int bt   = blockIdx.x;        // b*2 + t
    const int b    = bt >> 1;

    const f32x4 zf = {0.f, 0.f, 0.f, 0.f};

    auto load_tile = [&](const float* src) {   // 49x192 f32 -> f16 LDS tile
        for (int t = tid; t < NTOK * CDIM / 4; t += 512) {
            int row = t / 48, c4 = (t % 48) * 4;
            f4 v = *(const f4*)(src + row * CDIM + c4);
            half4_t h; h[0] = (_Float16)v[0]; h[1] = (_Float16)v[1];
                       h[2] = (_Float16)v[2]; h[3] = (_Float16)v[3];
            *(half4_t*)&XM[row][c4] = h;
        }
    };

    // zero pad rows 49..63 once (K/V pad tokens become finite bias; masked later)
    for (int idx = tid; idx < 15 * 200; idx += 512)
        XM[49 + idx / 200][idx % 200] = (_Float16)0.f;

    load_tile(x + (size_t)b * NTOK * CDIM);
    __syncthreads();

    // ---- Q = XM @ WQ^T + BQ -> Qs.  Wave owns 2 m-tiles x 3 n-tiles. ----
    {
        const int mt0 = (wave & 1) * 2;      // 0 or 2
        const int nt0 = (wave >> 1) * 3;     // 0,3,6,9
        f32x4 acc[2][3];
#pragma unroll
        for (int im = 0; im < 2; ++im)
#pragma unroll
            for (int j = 0; j < 3; ++j) acc[im][j] = zf;

        for (int ks = 0; ks < 6; ++ks) {
            const int k0 = ks * 32 + lq * 8;
            half8 a0 = *(const half8*)&XM[(mt0 + 0) * 16 + l16][k0];
            half8 a1 = *(const half8*)&XM[(mt0 + 1) * 16 + l16][k0];
            const _Float16* wb = WQ + (size_t)(nt0 * 16 + l16) * CDIM + k0;
            half8 b0 = *(const half8*)(wb);
            half8 b1 = *(const half8*)(wb + 16 * CDIM);
            half8 b2 = *(const half8*)(wb + 32 * CDIM);
            acc[0][0] = __builtin_amdgcn_mfma_f32_16x16x32_f16(a0, b0, acc[0][0], 0, 0, 0);
            acc[1][0] = __builtin_amdgcn_mfma_f32_16x16x32_f16(a1, b0, acc[1][0], 0, 0, 0);
            acc[0][1] = __builtin_amdgcn_mfma_f32_16x16x32_f16(a0, b1, acc[0][1], 0, 0, 0);
            acc[1][1] = __builtin_amdgcn_mfma_f32_16x16x32_f16(a1, b1, acc[1][1], 0, 0, 0);
            acc[0][2] = __builtin_amdgcn_mfma_f32_16x16x32_f16(a0, b2, acc[0][2], 0, 0, 0);
            acc[1][2] = __builtin_amdgcn_mfma_f32_16x16x32_f16(a1, b2, acc[1][2], 0, 0, 0);
        }
#pragma unroll
        for (int im = 0; im < 2; ++im)
#pragma unroll
            for (int j = 0; j < 3; ++j) {
                const int mt = mt0 + im, nt = nt0 + j;
                const float bv = BQ[nt * 16 + l16];
#pragma unroll
                for (int r = 0; r < 4; ++r)
                    Qs[mt * 16 + lq * 4 + r][nt * 16 + l16] = (_Float16)(acc[im][j][r] + bv);
            }
    }
    __syncthreads();

    load_tile(memory + (size_t)bt * NTOK * CDIM);
    __syncthreads();

    // ---- K,V = XM @ WKV^T + bkv.  Wave owns 4 m-tiles x 3 of 24 n-tiles. ----
    {
        const int nc0 = wave * 3;            // 0..21 (0..11 = K feats, 12..23 = V feats)
        f32x4 acc[3][4];
#pragma unroll
        for (int j = 0; j < 3; ++j)
#pragma unroll
            for (int m = 0; m < 4; ++m) acc[j][m] = zf;

        for (int ks = 0; ks < 6; ++ks) {
            const int k0 = ks * 32 + lq * 8;
            half8 a0 = *(const half8*)&XM[ 0 + l16][k0];
            half8 a1 = *(const half8*)&XM[16 + l16][k0];
            half8 a2 = *(const half8*)&XM[32 + l16][k0];
            half8 a3 = *(const half8*)&XM[48 + l16][k0];
            const _Float16* wb = WKV + (size_t)(nc0 * 16 + l16) * CDIM + k0;
            half8 b0 = *(const half8*)(wb);
            half8 b1 = *(const half8*)(wb + 16 * CDIM);
            half8 b2 = *(const half8*)(wb + 32 * CDIM);
            acc[0][0] = __builtin_amdgcn_mfma_f32_16x16x32_f16(a0, b0, acc[0][0], 0, 0, 0);
            acc[0][1] = __builtin_amdgcn_mfma_f32_16x16x32_f16(a1, b0, acc[0][1], 0, 0, 0);
            acc[0][2] = __builtin_amdgcn_mfma_f32_16x16x32_f16(a2, b0, acc[0][2], 0, 0, 0);
            acc[0][3] = __builtin_amdgcn_mfma_f32_16x16x32_f16(a3, b0, acc[0][3], 0, 0, 0);
            acc[1][0] = __builtin_amdgcn_mfma_f32_16x16x32_f16(a0, b1, acc[1][0], 0, 0, 0);
            acc[1][1] = __builtin_amdgcn_mfma_f32_16x16x32_f16(a1, b1, acc[1][1], 0, 0, 0);
            acc[1][2] = __builtin_amdgcn_mfma_f32_16x16x32_f16(a2, b1, acc[1][2], 0, 0, 0);
            acc[1][3] = __builtin_amdgcn_mfma_f32_16x16x32_f16(a3, b1, acc[1][3], 0, 0, 0);
            acc[2][0] = __builtin_amdgcn_mfma_f32_16x16x32_f16(a0, b2, acc[2][0], 0, 0, 0);
            acc[2][1] = __builtin_amdgcn_mfma_f32_16x16x32_f16(a1, b2, acc[2][1], 0, 0, 0);
            acc[2][2] = __builtin_amdgcn_mfma_f32_16x16x32_f16(a2, b2, acc[2][2], 0, 0, 0);
            acc[2][3] = __builtin_amdgcn_mfma_f32_16x16x32_f16(a3, b2, acc[2][3], 0, 0, 0);
        }
#pragma unroll
        for (int j = 0; j < 3; ++j) {
            const int ntc = nc0 + j;          // wave-uniform
            const int f   = ntc * 16 + l16;   // 0..383: K feats then V feats
            const float bv = bkv[f];
            if (ntc < 12) {                   // wave-uniform branch (waves 0..3)
#pragma unroll
                for (int m = 0; m < 4; ++m)
#pragma unroll
                    for (int r = 0; r < 4; ++r)
                        Ks[m * 16 + lq * 4 + r][f] = (_Float16)(acc[j][m][r] + bv);
            } else {                          // waves 4..7
#pragma unroll
                for (int m = 0; m < 4; ++m) {
                    half4_t pk;
#pragma unroll
                    for (int r = 0; r < 4; ++r) pk[r] = (_Float16)(acc[j][m][r] + bv);
                    *(half4_t*)&Vs[f - 192][m * 16 + lq * 4] = pk;   // transposed store
                }
            }
        }
    }
    __syncthreads();

    // ---- attention: 3 sequential head pairs; wave = (h2 = wave>>2, mt = wave&3) ----
    {
        const int h2 = wave >> 2, mt = wave & 3;
        const int row0 = mt * 16 + lq * 4;
        for (int p = 0; p < 3; ++p) {
            const int h = p * 2 + h2;
            // S = q k^T (K=32 -> single MFMA per n-tile)
            f32x4 s[4];
            half8 qa = *(const half8*)&Qs[mt * 16 + l16][h * 32 + lq * 8];
#pragma unroll
            for (int nt = 0; nt < 4; ++nt) {
                half8 kb = *(const half8*)&Ks[nt * 16 + l16][h * 32 + lq * 8];
                s[nt] = __builtin_amdgcn_mfma_f32_16x16x32_f16(qa, kb, zf, 0, 0, 0);
            }
            // + relative-position bias
#pragma unroll
            for (int nt = 0; nt < 4; ++nt)
#pragma unroll
                for (int r = 0; r < 4; ++r)
                    s[nt][r] += BIAS[(h * 64 + row0 + r) * 64 + nt * 16 + l16];
            // softmax per row (row = row0+r; cols spread over l16 x 4 n-tiles; kt>=49 masked)
#pragma unroll
            for (int r = 0; r < 4; ++r) {
                float v0 = s[0][r], v1 = s[1][r], v2 = s[2][r], v3 = s[3][r];
                float v3m = (l16 == 0) ? v3 : -3.0e38f;      // nt=3: only kt=48 valid
                float m = fmaxf(fmaxf(v0, v1), fmaxf(v2, v3m));
                for (int d2 = 1; d2 < 16; d2 <<= 1) m = fmaxf(m, __shfl_xor(m, d2, 64));
                v0 = __expf(v0 - m); v1 = __expf(v1 - m); v2 = __expf(v2 - m);
                v3 = (l16 == 0) ? __expf(v3 - m) : 0.f;
                float sm = v0 + v1 + v2 + v3;
                for (int d2 = 1; d2 < 16; d2 <<= 1) sm += __shfl_xor(sm, d2, 64);
                float inv = 1.f / sm;
                int rr = row0 + r;
                Ps[h2][rr][l16]      = (_Float16)(v0 * inv);
                Ps[h2][rr][16 + l16] = (_Float16)(v1 * inv);
                Ps[h2][rr][32 + l16] = (_Float16)(v2 * inv);
                Ps[h2][rr][48 + l16] = (_Float16)(v3 * inv);
            }
            __syncthreads();   // Ps D-layout write -> A-layout read (conservative)
            // O = P @ V
            f32x4 o0 = zf, o1 = zf;
#pragma unroll
            for (int ks2 = 0; ks2 < 2; ++ks2) {
                half8 pa  = *(const half8*)&Ps[h2][mt * 16 + l16][ks2 * 32 + lq * 8];
                half8 vb0 = *(const half8*)&Vs[h * 32 + l16][ks2 * 32 + lq * 8];
                half8 vb1 = *(const half8*)&Vs[h * 32 + 16 + l16][ks2 * 32 + lq * 8];
                o0 = __builtin_amdgcn_mfma_f32_16x16x32_f16(pa, vb0, o0, 0, 0, 0);
                o1 = __builtin_amdgcn_mfma_f32_16x16x32_f16(pa, vb1, o1, 0, 0, 0);
            }
#pragma unroll
            for (int r = 0; r < 4; ++r) {     // O -> XM (proj A operand), disjoint per wave
                XM[row0 + r][h * 32 + l16]      = (_Float16)o0[r];
                XM[row0 + r][h * 32 + 16 + l16] = (_Float16)o1[r];
            }
        }
    }
    __syncthreads();

    // ---- out = O @ WPJ^T + bproj.  Same 2x3 tiling as Q phase. ----
    {
        const int mt0 = (wave & 1) * 2;
        const int nt0 = (wave >> 1) * 3;
        f32x4 acc[2][3];
#pragma unroll
        for (int im = 0; im < 2; ++im)
#pragma unroll
            for (int j = 0; j < 3; ++j) acc[im][j] = zf;

        for (int ks = 0; ks < 6; ++ks) {
            const int k0 = ks * 32 + lq * 8;
            half8 a0 = *(const half8*)&XM[(mt0 + 0) * 16 + l16][k0];
            half8 a1 = *(const half8*)&XM[(mt0 + 1) * 16 + l16][k0];
            const _Float16* wb = WPJ + (size_t)(nt0 * 16 + l16) * CDIM + k0;
            half8 b0 = *(const half8*)(wb);
            half8 b1 = *(const half8*)(wb + 16 * CDIM);
            half8 b2 = *(const half8*)(wb + 32 * CDIM);
            acc[0][0] = __builtin_amdgcn_mfma_f32_16x16x32_f16(a0, b0, acc[0][0], 0, 0, 0);
            acc[1][0] = __builtin_amdgcn_mfma_f32_16x16x32_f16(a1, b0, acc[1][0], 0, 0, 0);
            acc[0][1] = __builtin_amdgcn_mfma_f32_16x16x32_f16(a0, b1, acc[0][1], 0, 0, 0);
            acc[1][1] = __builtin_amdgcn_mfma_f32_16x16x32_f16(a1, b1, acc[1][1], 0, 0, 0);
            acc[0][2] = __builtin_amdgcn_mfma_f32_16x16x32_f16(a0, b2, acc[0][2], 0, 0, 0);
            acc[1][2] = __builtin_amdgcn_mfma_f32_16x16x32_f16(a1, b2, acc[1][2], 0, 0, 0);
        }
        float* obase = out + (size_t)bt * NTOK * CDIM;
#pragma unroll
        for (int im = 0; im < 2; ++im)
#pragma unroll
            for (int j = 0; j < 3; ++j) {
                const int mt = mt0 + im, nt = nt0 + j;
                const float bv = bproj[nt * 16 + l16];
#pragma unroll
                for (int r = 0; r < 4; ++r) {
                    const int rr = mt * 16 + lq * 4 + r;
                    if (rr < NTOK)
                        obase[rr * CDIM + nt * 16 + l16] = acc[im][j][r] + bv;
                }
            }
    }
}

extern "C" void kernel_launch(void* const* d_in, const int* in_sizes, int n_in,
                              void* d_out, int out_size, void* d_ws, size_t ws_size,
                              hipStream_t stream)
{
    const float* x      = (const float*)d_in[0];
    const float* memory = (const float*)d_in[1];
    const float* w_q    = (const float*)d_in[2];
    const float* b_q    = (const float*)d_in[3];
    const float* w_kv   = (const float*)d_in[4];
    const float* b_kv   = (const float*)d_in[5];
    const float* w_proj = (const float*)d_in[6];
    const float* b_proj = (const float*)d_in[7];
    const float* rpb    = (const float*)d_in[8];
    float* out = (float*)d_out;

    char* wsp = (char*)d_ws;
    _Float16* WQ  = (_Float16*)(wsp + 0);
    _Float16* WKV = (_Float16*)(wsp + 73728);
    _Float16* WPJ = (_Float16*)(wsp + 221184);
    float*    BQ  = (float*)(wsp + 294912);
    float*    BIAS= (float*)(wsp + 295680);

    pack_kernel<<<673, 256, 0, stream>>>(w_q, b_q, w_kv, w_proj, rpb, WQ, WKV, WPJ, BQ, BIAS);
    attn_kernel<<<4096 * 2, 512, 0, stream>>>(x, memory, b_kv, b_proj, WQ, WKV, WPJ, BQ, BIAS, out);
}

// Round 2
// 1244.728 us; speedup vs baseline: 14.4044x; 1.0181x over previous
//
#include <hip/hip_runtime.h>

// ---------------------------------------------------------------------------
// Fused window cross-attention for MI355X (gfx950).
//   ref: q = (x Wq^T + bq) * scale ; kv = mem Wkv^T + bkv ; per-head
//        softmax(q k^T + rpb_bias) v ; out = o Wp^T + bp
// Shapes: B=4096, T=2, N=49 tokens, C=192, H=6 heads, d=32.
//
// R2: split the latency-bound fused kernel (1 block/CU, 8 barriers, 28 us of
// exposed latency per block) into two high-occupancy kernels:
//   qkv_kernel : Q = x@Wq (4096 blocks) / K,V = mem@Wkv (8192 blocks), f16
//                outputs in workspace, V stored transposed [feat][tok].
//                LDS 25.6 KB, 1 barrier.
//   attn2_kernel: reads Q/K/V MFMA fragments DIRECTLY from global (store
//                layout == fragment layout), softmax, PV, proj. LDS 44 KB
//                (Ps + O buffer), 2 barriers total; the per-head-pair barrier
//                is dropped (Ps rows are wave-private by construction).
// Runtime gate on ws_size (~504 MB needed); falls back to the R1 fused kernel.
// ---------------------------------------------------------------------------

typedef _Float16 half8  __attribute__((ext_vector_type(8)));  // 4 VGPRs, one MFMA A/B frag
typedef _Float16 half4_t __attribute__((ext_vector_type(4)));
typedef float    f32x4  __attribute__((ext_vector_type(4)));  // MFMA C/D frag
typedef float    f4     __attribute__((ext_vector_type(4)));

#define NTOK  49
#define CDIM  192
#define NHEAD 6
#define SCALE 0.17677669529663687f   // 1/sqrt(32)

// ws layout (bytes):
//   WQ   f16[192*192]          @ 0       (73728)   scale folded in
//   WKV  f16[384*192]          @ 73728   (147456)
//   WPJ  f16[192*192]          @ 221184  (73728)
//   BQ   f32[192]              @ 294912  (768)     scale folded in
//   BIAS f32[6][64][64]        @ 295680  (98304)   rpb gathered via REL_IDX
//   Qg   f16[4096][64][192]    @ 393984  (100.7 MB)  pad rows = bq (finite)
//   Kg   f16[8192][64][192]    @ +QG     (201.3 MB)  pad rows = bkv (masked)
//   Vg   f16[8192][192][64]    @ +KG     (201.3 MB)  transposed; pad toks finite, P=0 there

__global__ void pack_kernel(const float* __restrict__ wq, const float* __restrict__ bq,
                            const float* __restrict__ wkv, const float* __restrict__ wproj,
                            const float* __restrict__ rpb,
                            _Float16* __restrict__ WQ, _Float16* __restrict__ WKV,
                            _Float16* __restrict__ WPJ, float* __restrict__ BQ,
                            float* __restrict__ BIAS)
{
    int i = blockIdx.x * blockDim.x + threadIdx.x;
    if (i < 36864) {
        WQ[i] = (_Float16)(wq[i] * SCALE);
    } else if (i < 110592) {
        int j = i - 36864;  WKV[j] = (_Float16)wkv[j];
    } else if (i < 147456) {
        int j = i - 110592; WPJ[j] = (_Float16)wproj[j];
    } else if (i < 147648) {
        int j = i - 147456; BQ[j] = bq[j] * SCALE;
    } else if (i < 147648 + 24576) {
        int j = i - 147648;
        int h  = j >> 12;        // /4096
        int qt = (j >> 6) & 63;
        int kt = j & 63;
        float v = 0.f;
        if (qt < NTOK && kt < NTOK) {
            int ih = qt / 7, iw = qt % 7, jh = kt / 7, jw = kt % 7;
            int rel = (ih - jh + 6) * 13 + (iw - jw + 6);
            v = rpb[rel * NHEAD + h];
        }
        BIAS[j] = v;
    }
}

// Fragment conventions (m89/m120-verified, 16x16x32):
//   A frag: lane holds A[m = lane&15][k = (lane>>4)*8 + j], j=0..7  (contig 16B)
//   B frag: lane holds B[k = (lane>>4)*8 + j][n = lane&15]          (contig 16B in [n][k] storage)
//   D frag: lane holds D[row = (lane>>4)*4 + r][col = lane&15]

// ---------------------------------------------------------------------------
// Kernel A: QKV projection GEMMs. blockIdx < 8192: KV for bt; else Q for b.
// ---------------------------------------------------------------------------
__launch_bounds__(512)
__global__ void qkv_kernel(const float* __restrict__ x, const float* __restrict__ memory,
                           const float* __restrict__ bkv,
                           const _Float16* __restrict__ WQ, const _Float16* __restrict__ WKV,
                           const float* __restrict__ BQ,
                           _Float16* __restrict__ Qg, _Float16* __restrict__ Kg,
                           _Float16* __restrict__ Vg)
{
    __shared__ __align__(16) _Float16 XM[64][200];   // stride 200: 100 dw % 32 == 4 -> 2-way, free

    const int tid  = threadIdx.x;
    const int lane = tid & 63;
    const int wave = tid >> 6;          // 0..7
    const int l16  = lane & 15;
    const int lq   = lane >> 4;         // quad 0..3
    const bool isQ = blockIdx.x >= 8192;

    const f32x4 zf = {0.f, 0.f, 0.f, 0.f};

    // zero pad rows 49..63 (pad outputs become bias-only: finite, masked downstream)
    for (int idx = tid; idx < 15 * 200; idx += 512)
        XM[49 + idx / 200][idx % 200] = (_Float16)0.f;

    {   // stage input tile f32 -> f16
        const float* src = isQ ? (x + (size_t)(blockIdx.x - 8192) * NTOK * CDIM)
                               : (memory + (size_t)blockIdx.x * NTOK * CDIM);
        for (int t = tid; t < NTOK * CDIM / 4; t += 512) {
            int row = t / 48, c4 = (t % 48) * 4;
            f4 v = *(const f4*)(src + row * CDIM + c4);
            half4_t h; h[0] = (_Float16)v[0]; h[1] = (_Float16)v[1];
                       h[2] = (_Float16)v[2]; h[3] = (_Float16)v[3];
            *(half4_t*)&XM[row][c4] = h;
        }
    }
    __syncthreads();

    if (isQ) {
        // ---- Q = XM @ WQ^T + BQ -> Qg[b].  Wave owns 2 m-tiles x 3 n-tiles. ----
        const int b   = blockIdx.x - 8192;
        const int mt0 = (wave & 1) * 2;      // 0 or 2
        const int nt0 = (wave >> 1) * 3;     // 0,3,6,9
        f32x4 acc[2][3];
#pragma unroll
        for (int im = 0; im < 2; ++im)
#pragma unroll
            for (int j = 0; j < 3; ++j) acc[im][j] = zf;

        for (int ks = 0; ks < 6; ++ks) {
            const int k0 = ks * 32 + lq * 8;
            half8 a0 = *(const half8*)&XM[(mt0 + 0) * 16 + l16][k0];
            half8 a1 = *(const half8*)&XM[(mt0 + 1) * 16 + l16][k0];
            const _Float16* wb = WQ + (size_t)(nt0 * 16 + l16) * CDIM + k0;
            half8 b0 = *(const half8*)(wb);
            half8 b1 = *(const half8*)(wb + 16 * CDIM);
            half8 b2 = *(const half8*)(wb + 32 * CDIM);
            acc[0][0] = __builtin_amdgcn_mfma_f32_16x16x32_f16(a0, b0, acc[0][0], 0, 0, 0);
            acc[1][0] = __builtin_amdgcn_mfma_f32_16x16x32_f16(a1, b0, acc[1][0], 0, 0, 0);
            acc[0][1] = __builtin_amdgcn_mfma_f32_16x16x32_f16(a0, b1, acc[0][1], 0, 0, 0);
            acc[1][1] = __builtin_amdgcn_mfma_f32_16x16x32_f16(a1, b1, acc[1][1], 0, 0, 0);
            acc[0][2] = __builtin_amdgcn_mfma_f32_16x16x32_f16(a0, b2, acc[0][2], 0, 0, 0);
            acc[1][2] = __builtin_amdgcn_mfma_f32_16x16x32_f16(a1, b2, acc[1][2], 0, 0, 0);
        }
        _Float16* qbase = Qg + (size_t)b * 64 * CDIM;
#pragma unroll
        for (int im = 0; im < 2; ++im)
#pragma unroll
            for (int j = 0; j < 3; ++j) {
                const int mt = mt0 + im, nt = nt0 + j;
                const float bv = BQ[nt * 16 + l16];
#pragma unroll
                for (int r = 0; r < 4; ++r)
                    qbase[(mt * 16 + lq * 4 + r) * CDIM + nt * 16 + l16] =
                        (_Float16)(acc[im][j][r] + bv);
            }
    } else {
        // ---- K,V = XM @ WKV^T + bkv -> Kg[bt], Vg[bt] (V transposed). ----
        const int bt  = blockIdx.x;
        const int nc0 = wave * 3;            // 0..21 (0..11 = K feats, 12..23 = V feats)
        f32x4 acc[3][4];
#pragma unroll
        for (int j = 0; j < 3; ++j)
#pragma unroll
            for (int m = 0; m < 4; ++m) acc[j][m] = zf;

        for (int ks = 0; ks < 6; ++ks) {
            const int k0 = ks * 32 + lq * 8;
            half8 a0 = *(const half8*)&XM[ 0 + l16][k0];
            half8 a1 = *(const half8*)&XM[16 + l16][k0];
            half8 a2 = *(const half8*)&XM[32 + l16][k0];
            half8 a3 = *(const half8*)&XM[48 + l16][k0];
            const _Float16* wb = WKV + (size_t)(nc0 * 16 + l16) * CDIM + k0;
            half8 b0 = *(const half8*)(wb);
            half8 b1 = *(const half8*)(wb + 16 * CDIM);
            half8 b2 = *(const half8*)(wb + 32 * CDIM);
            acc[0][0] = __builtin_amdgcn_mfma_f32_16x16x32_f16(a0, b0, acc[0][0], 0, 0, 0);
            acc[0][1] = __builtin_amdgcn_mfma_f32_16x16x32_f16(a1, b0, acc[0][1], 0, 0, 0);
            acc[0][2] = __builtin_amdgcn_mfma_f32_16x16x32_f16(a2, b0, acc[0][2], 0, 0, 0);
            acc[0][3] = __builtin_amdgcn_mfma_f32_16x16x32_f16(a3, b0, acc[0][3], 0, 0, 0);
            acc[1][0] = __builtin_amdgcn_mfma_f32_16x16x32_f16(a0, b1, acc[1][0], 0, 0, 0);
            acc[1][1] = __builtin_amdgcn_mfma_f32_16x16x32_f16(a1, b1, acc[1][1], 0, 0, 0);
            acc[1][2] = __builtin_amdgcn_mfma_f32_16x16x32_f16(a2, b1, acc[1][2], 0, 0, 0);
            acc[1][3] = __builtin_amdgcn_mfma_f32_16x16x32_f16(a3, b1, acc[1][3], 0, 0, 0);
            acc[2][0] = __builtin_amdgcn_mfma_f32_16x16x32_f16(a0, b2, acc[2][0], 0, 0, 0);
            acc[2][1] = __builtin_amdgcn_mfma_f32_16x16x32_f16(a1, b2, acc[2][1], 0, 0, 0);
            acc[2][2] = __builtin_amdgcn_mfma_f32_16x16x32_f16(a2, b2, acc[2][2], 0, 0, 0);
            acc[2][3] = __builtin_amdgcn_mfma_f32_16x16x32_f16(a3, b2, acc[2][3], 0, 0, 0);
        }
        _Float16* kbase = Kg + (size_t)bt * 64 * CDIM;
        _Float16* vbase = Vg + (size_t)bt * CDIM * 64;
#pragma unroll
        for (int j = 0; j < 3; ++j) {
            const int ntc = nc0 + j;          // wave-uniform
            const int f   = ntc * 16 + l16;   // 0..383: K feats then V feats
            const float bv = bkv[f];
            if (ntc < 12) {                   // waves 0..3: K rows
#pragma unroll
                for (int m = 0; m < 4; ++m)
#pragma unroll
                    for (int r = 0; r < 4; ++r)
                        kbase[(m * 16 + lq * 4 + r) * CDIM + f] =
                            (_Float16)(acc[j][m][r] + bv);
            } else {                          // waves 4..7: V transposed [feat][tok]
                const int fv = f - 192;
#pragma unroll
                for (int m = 0; m < 4; ++m) {
                    half4_t pk;
#pragma unroll
                    for (int r = 0; r < 4; ++r) pk[r] = (_Float16)(acc[j][m][r] + bv);
                    *(half4_t*)&vbase[fv * 64 + m * 16 + lq * 4] = pk;
                }
            }
        }
    }
}

// ---------------------------------------------------------------------------
// Kernel B: attention + output projection. Block per bt, 8 waves = (h2, mt).
// Q/K/V fragments read directly from global (store layout == fragment layout).
// ---------------------------------------------------------------------------
__launch_bounds__(512)
__global__ void attn2_kernel(const float* __restrict__ bproj,
                             const _Float16* __restrict__ Qg, const _Float16* __restrict__ Kg,
                             const _Float16* __restrict__ Vg, const _Float16* __restrict__ WPJ,
                             const float* __restrict__ BIAS, float* __restrict__ out)
{
    __shared__ __align__(16) _Float16 Ps[2][64][72];   // softmax probs, wave-private rows
    __shared__ __align__(16) _Float16 OM[64][200];     // attention output O (proj A operand)

    const int tid  = threadIdx.x;
    const int lane = tid & 63;
    const int wave = tid >> 6;          // 0..7
    const int l16  = lane & 15;
    const int lq   = lane >> 4;
    const int bt   = blockIdx.x;
    const int b    = bt >> 1;

    const f32x4 zf = {0.f, 0.f, 0.f, 0.f};

    const int h2   = wave >> 2, mt = wave & 3;
    const int row0 = mt * 16 + lq * 4;

    const _Float16* qrow  = Qg + ((size_t)b * 64 + mt * 16 + l16) * CDIM;
    const _Float16* kb0   = Kg + (size_t)bt * 64 * CDIM;
    const _Float16* vb0g  = Vg + (size_t)bt * CDIM * 64;

#pragma unroll 1
    for (int p = 0; p < 3; ++p) {
        const int h = p * 2 + h2;
        const int koff = h * 32 + lq * 8;
        // S = q k^T
        half8 qa = *(const half8*)(qrow + koff);
        f32x4 s[4];
#pragma unroll
        for (int nt = 0; nt < 4; ++nt) {
            half8 kb = *(const half8*)(kb0 + (size_t)(nt * 16 + l16) * CDIM + koff);
            s[nt] = __builtin_amdgcn_mfma_f32_16x16x32_f16(qa, kb, zf, 0, 0, 0);
        }
        // + relative-position bias
#pragma unroll
        for (int nt = 0; nt < 4; ++nt)
#pragma unroll
            for (int r = 0; r < 4; ++r)
                s[nt][r] += BIAS[(h * 64 + row0 + r) * 64 + nt * 16 + l16];
        // softmax per row (cols spread over l16 x 4 n-tiles; kt>=49 masked)
#pragma unroll
        for (int r = 0; r < 4; ++r) {
            float v0 = s[0][r], v1 = s[1][r], v2 = s[2][r], v3 = s[3][r];
            float v3m = (l16 == 0) ? v3 : -3.0e38f;      // nt=3: only kt=48 valid
            float m = fmaxf(fmaxf(v0, v1), fmaxf(v2, v3m));
            for (int d2 = 1; d2 < 16; d2 <<= 1) m = fmaxf(m, __shfl_xor(m, d2, 64));
            v0 = __expf(v0 - m); v1 = __expf(v1 - m); v2 = __expf(v2 - m);
            v3 = (l16 == 0) ? __expf(v3 - m) : 0.f;
            float sm = v0 + v1 + v2 + v3;
            for (int d2 = 1; d2 < 16; d2 <<= 1) sm += __shfl_xor(sm, d2, 64);
            float inv = 1.f / sm;
            int rr = row0 + r;
            Ps[h2][rr][l16]      = (_Float16)(v0 * inv);
            Ps[h2][rr][16 + l16] = (_Float16)(v1 * inv);
            Ps[h2][rr][32 + l16] = (_Float16)(v2 * inv);
            Ps[h2][rr][48 + l16] = (_Float16)(v3 * inv);
        }
        // NO barrier: wave (h2,mt) writes Ps[h2] rows [mt*16, mt*16+16) and reads
        // exactly those rows below — intra-wave LDS dependency only (lgkmcnt).
        // O = P @ V
        f32x4 o0 = zf, o1 = zf;
#pragma unroll
        for (int ks2 = 0; ks2 < 2; ++ks2) {
            half8 pa  = *(const half8*)&Ps[h2][mt * 16 + l16][ks2 * 32 + lq * 8];
            half8 vb0 = *(const half8*)(vb0g + (size_t)(h * 32 + l16) * 64      + ks2 * 32 + lq * 8);
            half8 vb1 = *(const half8*)(vb0g + (size_t)(h * 32 + 16 + l16) * 64 + ks2 * 32 + lq * 8);
            o0 = __builtin_amdgcn_mfma_f32_16x16x32_f16(pa, vb0, o0, 0, 0, 0);
            o1 = __builtin_amdgcn_mfma_f32_16x16x32_f16(pa, vb1, o1, 0, 0, 0);
        }
#pragma unroll
        for (int r = 0; r < 4; ++r) {     // O -> OM, disjoint per (wave, head)
            OM[row0 + r][h * 32 + l16]      = (_Float16)o0[r];
            OM[row0 + r][h * 32 + 16 + l16] = (_Float16)o1[r];
        }
    }
    __syncthreads();

    // ---- out = O @ WPJ^T + bproj.  Wave owns 2 m-tiles x 3 n-tiles. ----
    {
        const int mt0 = (wave & 1) * 2;
        const int nt0 = (wave >> 1) * 3;
        f32x4 acc[2][3];
#pragma unroll
        for (int im = 0; im < 2; ++im)
#pragma unroll
            for (int j = 0; j < 3; ++j) acc[im][j] = zf;

        for (int ks = 0; ks < 6; ++ks) {
            const int k0 = ks * 32 + lq * 8;
            half8 a0 = *(const half8*)&OM[(mt0 + 0) * 16 + l16][k0];
            half8 a1 = *(const half8*)&OM[(mt0 + 1) * 16 + l16][k0];
            const _Float16* wb = WPJ + (size_t)(nt0 * 16 + l16) * CDIM + k0;
            half8 b0 = *(const half8*)(wb);
            half8 b1 = *(const half8*)(wb + 16 * CDIM);
            half8 b2 = *(const half8*)(wb + 32 * CDIM);
            acc[0][0] = __builtin_amdgcn_mfma_f32_16x16x32_f16(a0, b0, acc[0][0], 0, 0, 0);
            acc[1][0] = __builtin_amdgcn_mfma_f32_16x16x32_f16(a1, b0, acc[1][0], 0, 0, 0);
            acc[0][1] = __builtin_amdgcn_mfma_f32_16x16x32_f16(a0, b1, acc[0][1], 0, 0, 0);
            acc[1][1] = __builtin_amdgcn_mfma_f32_16x16x32_f16(a1, b1, acc[1][1], 0, 0, 0);
            acc[0][2] = __builtin_amdgcn_mfma_f32_16x16x32_f16(a0, b2, acc[0][2], 0, 0, 0);
            acc[1][2] = __builtin_amdgcn_mfma_f32_16x16x32_f16(a1, b2, acc[1][2], 0, 0, 0);
        }
        float* obase = out + (size_t)bt * NTOK * CDIM;
#pragma unroll
        for (int im = 0; im < 2; ++im)
#pragma unroll
            for (int j = 0; j < 3; ++j) {
                const int mt = mt0 + im, nt = nt0 + j;
                const float bv = bproj[nt * 16 + l16];
#pragma unroll
                for (int r = 0; r < 4; ++r) {
                    const int rr = mt * 16 + lq * 4 + r;
                    if (rr < NTOK)
                        obase[rr * CDIM + nt * 16 + l16] = acc[im][j][r] + bv;
                }
            }
    }
}

// ---------------------------------------------------------------------------
// Fallback: R1 fused kernel (verbatim), used when workspace is too small.
// ---------------------------------------------------------------------------
__launch_bounds__(512)
__global__ void attn_kernel(const float* __restrict__ x, const float* __restrict__ memory,
                            const float* __restrict__ bkv, const float* __restrict__ bproj,
                            const _Float16* __restrict__ WQ, const _Float16* __restrict__ WKV,
                            const _Float16* __restrict__ WPJ, const float* __restrict__ BQ,
                            const float* __restrict__ BIAS, float* __restrict__ out)
{
    __shared__ __align__(16) _Float16 XM[64][200];
    __shared__ __align__(16) _Float16 Qs[64][200];
    __shared__ __align__(16) _Float16 Ks[64][200];
    __shared__ __align__(16) _Float16 Vs[192][72];
    __shared__ __align__(16) _Float16 Ps[2][64][72];

    const int tid  = threadIdx.x;
    const int lane = tid & 63;
    const int wave = tid >> 6;
    const int l16  = lane & 15;
    const int lq   = lane >> 4;
    const int bt   = blockIdx.x;
    const int b    = bt >> 1;

    const f32x4 zf = {0.f, 0.f, 0.f, 0.f};

    auto load_tile = [&](const float* src) {
        for (int t = tid; t < NTOK * CDIM / 4; t += 512) {
            int row = t / 48, c4 = (t % 48) * 4;
            f4 v = *(const f4*)(src + row * CDIM + c4);
            half4_t h; h[0] = (_Float16)v[0]; h[1] = (_Float16)v[1];
                       h[2] = (_Float16)v[2]; h[3] = (_Float16)v[3];
            *(half4_t*)&XM[row][c4] = h;
        }
    };

    for (int idx = tid; idx < 15 * 200; idx += 512)
        XM[49 + idx / 200][idx % 200] = (_Float16)0.f;

    load_tile(x + (size_t)b * NTOK * CDIM);
    __syncthreads();

    {
        const int mt0 = (wave & 1) * 2;
        const int nt0 = (wave >> 1) * 3;
        f32x4 acc[2][3];
#pragma unroll
        for (int im = 0; im < 2; ++im)
#pragma unroll
            for (int j = 0; j < 3; ++j) acc[im][j] = zf;

        for (int ks = 0; ks < 6; ++ks) {
            const int k0 = ks * 32 + lq * 8;
            half8 a0 = *(const half8*)&XM[(mt0 + 0) * 16 + l16][k0];
            half8 a1 = *(const half8*)&XM[(mt0 + 1) * 16 + l16][k0];
            const _Float16* wb = WQ + (size_t)(nt0 * 16 + l16) * CDIM + k0;
            half8 b0 = *(const half8*)(wb);
            half8 b1 = *(const half8*)(wb + 16 * CDIM);
            half8 b2 = *(const half8*)(wb + 32 * CDIM);
            acc[0][0] = __builtin_amdgcn_mfma_f32_16x16x32_f16(a0, b0, acc[0][0], 0, 0, 0);
            acc[1][0] = __builtin_amdgcn_mfma_f32_16x16x32_f16(a1, b0, acc[1][0], 0, 0, 0);
            acc[0][1] = __builtin_amdgcn_mfma_f32_16x16x32_f16(a0, b1, acc[0][1], 0, 0, 0);
            acc[1][1] = __builtin_amdgcn_mfma_f32_16x16x32_f16(a1, b1, acc[1][1], 0, 0, 0);
            acc[0][2] = __builtin_amdgcn_mfma_f32_16x16x32_f16(a0, b2, acc[0][2], 0, 0, 0);
            acc[1][2] = __builtin_amdgcn_mfma_f32_16x16x32_f16(a1, b2, acc[1][2], 0, 0, 0);
        }
#pragma unroll
        for (int im = 0; im < 2; ++im)
#pragma unroll
            for (int j = 0; j < 3; ++j) {
                const int mt = mt0 + im, nt = nt0 + j;
                const float bv = BQ[nt * 16 + l16];
#pragma unroll
                for (int r = 0; r < 4; ++r)
                    Qs[mt * 16 + lq * 4 + r][nt * 16 + l16] = (_Float16)(acc[im][j][r] + bv);
            }
    }
    __syncthreads();

    load_tile(memory + (size_t)bt * NTOK * CDIM);
    __syncthreads();

    {
        const int nc0 = wave * 3;
        f32x4 acc[3][4];
#pragma unroll
        for (int j = 0; j < 3; ++j)
#pragma unroll
            for (int m = 0; m < 4; ++m) acc[j][m] = zf;

        for (int ks = 0; ks < 6; ++ks) {
            const int k0 = ks * 32 + lq * 8;
            half8 a0 = *(const half8*)&XM[ 0 + l16][k0];
            half8 a1 = *(const half8*)&XM[16 + l16][k0];
            half8 a2 = *(const half8*)&XM[32 + l16][k0];
            half8 a3 = *(const half8*)&XM[48 + l16][k0];
            const _Float16* wb = WKV + (size_t)(nc0 * 16 + l16) * CDIM + k0;
            half8 b0 = *(const half8*)(wb);
            half8 b1 = *(const half8*)(wb + 16 * CDIM);
            half8 b2 = *(const half8*)(wb + 32 * CDIM);
            acc[0][0] = __builtin_amdgcn_mfma_f32_16x16x32_f16(a0, b0, acc[0][0], 0, 0, 0);
            acc[0][1] = __builtin_amdgcn_mfma_f32_16x16x32_f16(a1, b0, acc[0][1], 0, 0, 0);
            acc[0][2] = __builtin_amdgcn_mfma_f32_16x16x32_f16(a2, b0, acc[0][2], 0, 0, 0);
            acc[0][3] = __builtin_amdgcn_mfma_f32_16x16x32_f16(a3, b0, acc[0][3], 0, 0, 0);
            acc[1][0] = __builtin_amdgcn_mfma_f32_16x16x32_f16(a0, b1, acc[1][0], 0, 0, 0);
            acc[1][1] = __builtin_amdgcn_mfma_f32_16x16x32_f16(a1, b1, acc[1][1], 0, 0, 0);
            acc[1][2] = __builtin_amdgcn_mfma_f32_16x16x32_f16(a2, b1, acc[1][2], 0, 0, 0);
            acc[1][3] = __builtin_amdgcn_mfma_f32_16x16x32_f16(a3, b1, acc[1][3], 0, 0, 0);
            acc[2][0] = __builtin_amdgcn_mfma_f32_16x16x32_f16(a0, b2, acc[2][0], 0, 0, 0);
            acc[2][1] = __builtin_amdgcn_mfma_f32_16x16x32_f16(a1, b2, acc[2][1], 0, 0, 0);
            acc[2][2] = __builtin_amdgcn_mfma_f32_16x16x32_f16(a2, b2, acc[2][2], 0, 0, 0);
            acc[2][3] = __builtin_amdgcn_mfma_f32_16x16x32_f16(a3, b2, acc[2][3], 0, 0, 0);
        }
#pragma unroll
        for (int j = 0; j < 3; ++j) {
            const int ntc = nc0 + j;
            const int f   = ntc * 16 + l16;
            const float bv = bkv[f];
            if (ntc < 12) {
#pragma unroll
                for (int m = 0; m < 4; ++m)
#pragma unroll
                    for (int r = 0; r < 4; ++r)
                        Ks[m * 16 + lq * 4 + r][f] = (_Float16)(acc[j][m][r] + bv);
            } else {
#pragma unroll
                for (int m = 0; m < 4; ++m) {
                    half4_t pk;
#pragma unroll
                    for (int r = 0; r < 4; ++r) pk[r] = (_Float16)(acc[j][m][r] + bv);
                    *(half4_t*)&Vs[f - 192][m * 16 + lq * 4] = pk;
                }
            }
        }
    }
    __syncthreads();

    {
        const int h2 = wave >> 2, mt = wave & 3;
        const int row0 = mt * 16 + lq * 4;
        for (int p = 0; p < 3; ++p) {
            const int h = p * 2 + h2;
            f32x4 s[4];
            half8 qa = *(const half8*)&Qs[mt * 16 + l16][h * 32 + lq * 8];
#pragma unroll
            for (int nt = 0; nt < 4; ++nt) {
                half8 kb = *(const half8*)&Ks[nt * 16 + l16][h * 32 + lq * 8];
                s[nt] = __builtin_amdgcn_mfma_f32_16x16x32_f16(qa, kb, zf, 0, 0, 0);
            }
#pragma unroll
            for (int nt = 0; nt < 4; ++nt)
#pragma unroll
                for (int r = 0; r < 4; ++r)
                    s[nt][r] += BIAS[(h * 64 + row0 + r) * 64 + nt * 16 + l16];
#pragma unroll
            for (int r = 0; r < 4; ++r) {
                float v0 = s[0][r], v1 = s[1][r], v2 = s[2][r], v3 = s[3][r];
                float v3m = (l16 == 0) ? v3 : -3.0e38f;
                float m = fmaxf(fmaxf(v0, v1), fmaxf(v2, v3m));
                for (int d2 = 1; d2 < 16; d2 <<= 1) m = fmaxf(m, __shfl_xor(m, d2, 64));
                v0 = __expf(v0 - m); v1 = __expf(v1 - m); v2 = __expf(v2 - m);
                v3 = (l16 == 0) ? __expf(v3 - m) : 0.f;
                float sm = v0 + v1 + v2 + v3;
                for (int d2 = 1; d2 < 16; d2 <<= 1) sm += __shfl_xor(sm, d2, 64);
                float inv = 1.f / sm;
                int rr = row0 + r;
                Ps[h2][rr][l16]      = (_Float16)(v0 * inv);
                Ps[h2][rr][16 + l16] = (_Float16)(v1 * inv);
                Ps[h2][rr][32 + l16] = (_Float16)(v2 * inv);
                Ps[h2][rr][48 + l16] = (_Float16)(v3 * inv);
            }
            __syncthreads();
            f32x4 o0 = zf, o1 = zf;
#pragma unroll
            for (int ks2 = 0; ks2 < 2; ++ks2) {
                half8 pa  = *(const half8*)&Ps[h2][mt * 16 + l16][ks2 * 32 + lq * 8];
                half8 vb0 = *(const half8*)&Vs[h * 32 + l16][ks2 * 32 + lq * 8];
                half8 vb1 = *(const half8*)&Vs[h * 32 + 16 + l16][ks2 * 32 + lq * 8];
                o0 = __builtin_amdgcn_mfma_f32_16x16x32_f16(pa, vb0, o0, 0, 0, 0);
                o1 = __builtin_amdgcn_mfma_f32_16x16x32_f16(pa, vb1, o1, 0, 0, 0);
            }
#pragma unroll
            for (int r = 0; r < 4; ++r) {
                XM[row0 + r][h * 32 + l16]      = (_Float16)o0[r];
                XM[row0 + r][h * 32 + 16 + l16] = (_Float16)o1[r];
            }
        }
    }
    __syncthreads();

    {
        const int mt0 = (wave & 1) * 2;
        const int nt0 = (wave >> 1) * 3;
        f32x4 acc[2][3];
#pragma unroll
        for (int im = 0; im < 2; ++im)
#pragma unroll
            for (int j = 0; j < 3; ++j) acc[im][j] = zf;

        for (int ks = 0; ks < 6; ++ks) {
            const int k0 = ks * 32 + lq * 8;
            half8 a0 = *(const half8*)&XM[(mt0 + 0) * 16 + l16][k0];
            half8 a1 = *(const half8*)&XM[(mt0 + 1) * 16 + l16][k0];
            const _Float16* wb = WPJ + (size_t)(nt0 * 16 + l16) * CDIM + k0;
            half8 b0 = *(const half8*)(wb);
            half8 b1 = *(const half8*)(wb + 16 * CDIM);
            half8 b2 = *(const half8*)(wb + 32 * CDIM);
            acc[0][0] = __builtin_amdgcn_mfma_f32_16x16x32_f16(a0, b0, acc[0][0], 0, 0, 0);
            acc[1][0] = __builtin_amdgcn_mfma_f32_16x16x32_f16(a1, b0, acc[1][0], 0, 0, 0);
            acc[0][1] = __builtin_amdgcn_mfma_f32_16x16x32_f16(a0, b1, acc[0][1], 0, 0, 0);
            acc[1][1] = __builtin_amdgcn_mfma_f32_16x16x32_f16(a1, b1, acc[1][1], 0, 0, 0);
            acc[0][2] = __builtin_amdgcn_mfma_f32_16x16x32_f16(a0, b2, acc[0][2], 0, 0, 0);
            acc[1][2] = __builtin_amdgcn_mfma_f32_16x16x32_f16(a1, b2, acc[1][2], 0, 0, 0);
        }
        float* obase = out + (size_t)bt * NTOK * CDIM;
#pragma unroll
        for (int im = 0; im < 2; ++im)
#pragma unroll
            for (int j = 0; j < 3; ++j) {
                const int mt = mt0 + im, nt = nt0 + j;
                const float bv = bproj[nt * 16 + l16];
#pragma unroll
                for (int r = 0; r < 4; ++r) {
                    const int rr = mt * 16 + lq * 4 + r;
                    if (rr < NTOK)
                        obase[rr * CDIM + nt * 16 + l16] = acc[im][j][r] + bv;
                }
            }
    }
}

extern "C" void kernel_launch(void* const* d_in, const int* in_sizes, int n_in,
                              void* d_out, int out_size, void* d_ws, size_t ws_size,
                              hipStream_t stream)
{
    const float* x      = (const float*)d_in[0];
    const float* memory = (const float*)d_in[1];
    const float* w_q    = (const float*)d_in[2];
    const float* b_q    = (const float*)d_in[3];
    const float* w_kv   = (const float*)d_in[4];
    const float* b_kv   = (const float*)d_in[5];
    const float* w_proj = (const float*)d_in[6];
    const float* b_proj = (const float*)d_in[7];
    const float* rpb    = (const float*)d_in[8];
    float* out = (float*)d_out;

    char* wsp = (char*)d_ws;
    _Float16* WQ  = (_Float16*)(wsp + 0);
    _Float16* WKV = (_Float16*)(wsp + 73728);
    _Float16* WPJ = (_Float16*)(wsp + 221184);
    float*    BQ  = (float*)(wsp + 294912);
    float*    BIAS= (float*)(wsp + 295680);

    const size_t QG_OFF = 393984;                                   // 256-aligned
    const size_t QG_SZ  = (size_t)4096 * 64 * CDIM * sizeof(_Float16);
    const size_t KG_OFF = QG_OFF + QG_SZ;
    const size_t KG_SZ  = (size_t)8192 * 64 * CDIM * sizeof(_Float16);
    const size_t VG_OFF = KG_OFF + KG_SZ;
    const size_t VG_SZ  = (size_t)8192 * CDIM * 64 * sizeof(_Float16);
    const size_t NEED   = VG_OFF + VG_SZ;                           // ~503.7 MB

    pack_kernel<<<673, 256, 0, stream>>>(w_q, b_q, w_kv, w_proj, rpb, WQ, WKV, WPJ, BQ, BIAS);

    if (ws_size >= NEED) {
        _Float16* Qg = (_Float16*)(wsp + QG_OFF);
        _Float16* Kg = (_Float16*)(wsp + KG_OFF);
        _Float16* Vg = (_Float16*)(wsp + VG_OFF);
        qkv_kernel <<<12288, 512, 0, stream>>>(x, memory, b_kv, WQ, WKV, BQ, Qg, Kg, Vg);
        attn2_kernel<<<8192, 512, 0, stream>>>(b_proj, Qg, Kg, Vg, WPJ, BIAS, out);
    } else {
        attn_kernel<<<4096 * 2, 512, 0, stream>>>(x, memory, b_kv, b_proj, WQ, WKV, WPJ, BQ, BIAS, out);
    }
}